// Round 8
// baseline (928.842 us; speedup 1.0000x reference)
//
#include <hip/hip_runtime.h>
#include <stdint.h>
#include <stddef.h>

#define NN 150000   // nodes
#define NPAD 150016 // padded rows (= 586 * 256)
#define NE 300000   // edges
#define NG 256      // graphs
#define DE 128      // embedding dim
#define DH 256      // hidden dim

typedef unsigned short bf16_t;
typedef __attribute__((ext_vector_type(8))) short bf16x8;
typedef __attribute__((ext_vector_type(4))) float f32x4;

__device__ __forceinline__ float bf2f(unsigned int u) {
    union { unsigned int i; float f; } v; v.i = u << 16; return v.f;
}
__device__ __forceinline__ bf16_t f2bf(float f) {
    union { float f; unsigned int i; } v; v.f = f;
    unsigned int x = v.i;
    return (bf16_t)((x + 0x7fffu + ((x >> 16) & 1u)) >> 16);   // RNE
}

// ---------------------------------------------------------------- utility

__global__ void k_zero(int* __restrict__ p, int n) {
    int i = blockIdx.x * blockDim.x + threadIdx.x;
    if (i < n) p[i] = 0;
}

// ---------------------------------------------------------------- precompute

__global__ void k_hist(const int* __restrict__ dst, int* __restrict__ cnt) {
    int e = blockIdx.x * blockDim.x + threadIdx.x;
    if (e < NE) atomicAdd(&cnt[dst[e]], 1);
}

__global__ void k_dinv(const int* __restrict__ cnt, float* __restrict__ dinv) {
    int i = blockIdx.x * blockDim.x + threadIdx.x;
    if (i < NN) dinv[i] = rsqrtf((float)(cnt[i] + 1));  // +1 self-loop; deg>=1
}

#define SCAN_CHUNK 1024
__global__ void k_scan1(const int* __restrict__ cnt, int* __restrict__ bsum) {
    __shared__ int sd[256];
    int base = blockIdx.x * SCAN_CHUNK;
    int t = threadIdx.x;
    int s = 0;
#pragma unroll
    for (int j = 0; j < 4; j++) {
        int i = base + t * 4 + j;
        if (i < NN) s += cnt[i];
    }
    sd[t] = s; __syncthreads();
    for (int off = 128; off > 0; off >>= 1) {
        if (t < off) sd[t] += sd[t + off];
        __syncthreads();
    }
    if (t == 0) bsum[blockIdx.x] = sd[0];
}

__global__ void k_scan2(int* __restrict__ bsum, int nb) {
    if (threadIdx.x == 0) {
        int acc = 0;
        for (int b = 0; b < nb; b++) { int v = bsum[b]; bsum[b] = acc; acc += v; }
    }
}

__global__ void k_scan3(const int* __restrict__ cnt, const int* __restrict__ bsum,
                        int* __restrict__ rowptr) {
    __shared__ int sd[256];
    int base = blockIdx.x * SCAN_CHUNK;
    int t = threadIdx.x;
    int v[4]; int s = 0;
#pragma unroll
    for (int j = 0; j < 4; j++) {
        int i = base + t * 4 + j;
        v[j] = (i < NN) ? cnt[i] : 0;
        s += v[j];
    }
    sd[t] = s; __syncthreads();
    for (int off = 1; off < 256; off <<= 1) {
        int x = (t >= off) ? sd[t - off] : 0;
        __syncthreads();
        sd[t] += x;
        __syncthreads();
    }
    int pre = bsum[blockIdx.x] + ((t == 0) ? 0 : sd[t - 1]);
#pragma unroll
    for (int j = 0; j < 4; j++) {
        int i = base + t * 4 + j;
        if (i < NN) { rowptr[i] = pre; pre += v[j]; }
    }
    if (blockIdx.x == 0 && t == 0) rowptr[NN] = NE;
}

__global__ void k_scatter(const int* __restrict__ src, const int* __restrict__ dst,
                          const int* __restrict__ rowptr, int* __restrict__ fill,
                          int* __restrict__ col) {
    int e = blockIdx.x * blockDim.x + threadIdx.x;
    if (e < NE) {
        int d = dst[e];
        int p = rowptr[d] + atomicAdd(&fill[d], 1);
        col[p] = src[e];
    }
}

__global__ void k_gstart(const int* __restrict__ batch, int* __restrict__ gstart) {
    int i = blockIdx.x * blockDim.x + threadIdx.x;
    if (i >= NN) return;
    int g = batch[i];
    int gp = (i == 0) ? -1 : batch[i - 1];
    for (int gg = gp + 1; gg <= g; ++gg) gstart[gg] = i;
    if (i == NN - 1) {
        for (int gg = g + 1; gg <= NG; ++gg) gstart[gg] = NN;
    }
}

// ------------------------------------------------------- weight fragment prep
// W[K][256] fp32 -> frag-ordered bf16 hi/lo, linear in q = nt*KS + ks (nt 0..15):
// element (q,l,j) = W[ks*32 + (l>>4)*8 + j][nt*16 + (l&15)]

__global__ void k_wprep(const float* __restrict__ W, int KS,
                        bf16_t* __restrict__ whi, bf16_t* __restrict__ wlo) {
    int tid = blockIdx.x * blockDim.x + threadIdx.x;
    int total = 16 * KS * 64;
    if (tid >= total) return;
    int l = tid & 63, q = tid >> 6;
    int ks = q % KS;
    int nt = q / KS;
    int row0 = ks * 32 + (l >> 4) * 8;
    int colc = nt * 16 + (l & 15);
    unsigned hi[8], lo[8];
#pragma unroll
    for (int j = 0; j < 8; j++) {
        float v = W[(size_t)(row0 + j) * DH + colc];
        bf16_t h = f2bf(v);
        float rem = v - bf2f(h);
        hi[j] = h;
        lo[j] = f2bf(rem);
    }
    uint4 ph, pl;
    ph.x = hi[0] | (hi[1] << 16); ph.y = hi[2] | (hi[3] << 16);
    ph.z = hi[4] | (hi[5] << 16); ph.w = hi[6] | (hi[7] << 16);
    pl.x = lo[0] | (lo[1] << 16); pl.y = lo[2] | (lo[3] << 16);
    pl.z = lo[4] | (lo[5] << 16); pl.w = lo[6] | (lo[7] << 16);
    ((uint4*)whi)[q * 64 + l] = ph;
    ((uint4*)wlo)[q * 64 + l] = pl;
}

__device__ __forceinline__ void unpack8(uint4 u, float* f) {
    f[0] = bf2f(u.x & 0xffffu); f[1] = bf2f(u.x >> 16);
    f[2] = bf2f(u.y & 0xffffu); f[3] = bf2f(u.y >> 16);
    f[4] = bf2f(u.z & 0xffffu); f[5] = bf2f(u.z >> 16);
    f[6] = bf2f(u.w & 0xffffu); f[7] = bf2f(u.w >> 16);
}

// ------------------------------------------- fused aggregate + GEMM + ReLU
// C[NPAD x 256] = relu( (GCN-agg X)[NPAD x K] @ W[K x 256] + bias )
// Block: 512 threads = 8 waves; block tile = 256 rows x 256 cols.
// Agg is COOPERATIVE via LDS (coalesced, like k_agg): two phases of 128 rows
// each write a padded [128][K+8] bf16 tile; waves ds_read their A-frags into
// VGPRs. W_hi nt 0..7 staged in LDS; W_hi nt 8..15 + all W_lo streamed from
// L2. Epilogue staged through the (freed) sA region, flushed coalesced.

template <int KS, bool EMB>
__global__ __launch_bounds__(512) void k_fused(
    const bf16_t* __restrict__ X, const float* __restrict__ emb,
    const int* __restrict__ nids, const float* __restrict__ dinv,
    const int* __restrict__ rowptr, const int* __restrict__ col,
    const bf16_t* __restrict__ whi, const bf16_t* __restrict__ wlo,
    const float* __restrict__ bias, bf16_t* __restrict__ C)
{
    constexpr int K  = KS * 32;
    constexpr int CH = K / 8;                 // 8-elem chunks per row
    constexpr int RS = K + 8;                 // sA row stride (elems), pad kills conflicts
    constexpr int SWB = 8 * KS * 512 * 2;     // W_hi LDS bytes (nt 0..7)
    constexpr int SAB = 128 * RS * 2;         // agg tile bytes
    constexpr int SCB = 256 * 72 * 2;         // C staging bytes (64 cols + pad)
    constexpr int AMAX = (SAB > SCB) ? SAB : SCB;
    __shared__ __align__(16) char smem[SWB + AMAX];
    bf16_t* sW = (bf16_t*)smem;
    bf16_t* sA = (bf16_t*)(smem + SWB);
    bf16_t* sC = (bf16_t*)(smem + SWB);

    const int t = threadIdx.x;
    const int lane = t & 63;
    const int wave = t >> 6;                  // 0..7
    const int br0 = blockIdx.x * 256;

    // stage W_hi nt 0..7 into LDS (linear)
    {
        const uint4* gsrc = (const uint4*)whi;
        uint4* sdst = (uint4*)sW;
#pragma unroll
        for (int i = 0; i < SWB / 16 / 512; i++)
            sdst[t + i * 512] = gsrc[t + i * 512];
    }

    const int koff = (lane >> 4) * 8;
    bf16x8 a[2][KS];

    // ---- two agg phases of 128 rows each ----
#pragma unroll 1
    for (int p = 0; p < 2; p++) {
        const int pr0 = br0 + p * 128;
#pragma unroll 1
        for (int it = 0; it < 128 * CH / 512; it++) {
            const int item = t + it * 512;
            const int ln = item / CH;
            const int c  = item % CH;
            const int row = pr0 + ln;
            uint4 o = make_uint4(0, 0, 0, 0);
            if (row < NN) {
                const float di = dinv[row];
                float acc[8];
                if (EMB) {
                    const float4* sp = (const float4*)(emb + (size_t)nids[row] * DE + c * 8);
                    float4 u0 = sp[0], u1 = sp[1];
                    acc[0] = u0.x; acc[1] = u0.y; acc[2] = u0.z; acc[3] = u0.w;
                    acc[4] = u1.x; acc[5] = u1.y; acc[6] = u1.z; acc[7] = u1.w;
                } else {
                    unpack8(*(const uint4*)(X + (size_t)row * K + c * 8), acc);
                }
#pragma unroll
                for (int j = 0; j < 8; j++) acc[j] *= di;
                const int e0 = rowptr[row], e1 = rowptr[row + 1];
                for (int e = e0; e < e1; ++e) {
                    const int sn = col[e];
                    const float ds = dinv[sn];
                    float f[8];
                    if (EMB) {
                        const float4* sp = (const float4*)(emb + (size_t)nids[sn] * DE + c * 8);
                        float4 u0 = sp[0], u1 = sp[1];
                        f[0] = u0.x; f[1] = u0.y; f[2] = u0.z; f[3] = u0.w;
                        f[4] = u1.x; f[5] = u1.y; f[6] = u1.z; f[7] = u1.w;
                    } else {
                        unpack8(*(const uint4*)(X + (size_t)sn * K + c * 8), f);
                    }
#pragma unroll
                    for (int j = 0; j < 8; j++) acc[j] = fmaf(ds, f[j], acc[j]);
                }
                o.x = (unsigned)f2bf(di * acc[0]) | ((unsigned)f2bf(di * acc[1]) << 16);
                o.y = (unsigned)f2bf(di * acc[2]) | ((unsigned)f2bf(di * acc[3]) << 16);
                o.z = (unsigned)f2bf(di * acc[4]) | ((unsigned)f2bf(di * acc[5]) << 16);
                o.w = (unsigned)f2bf(di * acc[6]) | ((unsigned)f2bf(di * acc[7]) << 16);
            }
            *(uint4*)(sA + ln * RS + c * 8) = o;
        }
        __syncthreads();
        // waves p*4 .. p*4+3 own these 128 rows: load A-frags from LDS
        if ((wave >> 2) == p) {
            const int lw = wave & 3;
#pragma unroll
            for (int s = 0; s < 2; s++) {
                const int ln = lw * 32 + s * 16 + (lane & 15);
#pragma unroll
                for (int ks = 0; ks < KS; ks++)
                    a[s][ks] = *(const bf16x8*)(sA + ln * RS + koff + ks * 32);
            }
        }
        __syncthreads();
    }

    // ---- MFMA over 16 nt, staged epilogue every 4 nt ----
    const int cl = lane & 15;
    const int rl = (lane >> 4) * 4;
    const int rbase = wave * 32;

#pragma unroll 1
    for (int g = 0; g < 4; g++) {
#pragma unroll
        for (int nti = 0; nti < 4; nti++) {
            const int nt = g * 4 + nti;
            f32x4 ah0 = (f32x4){0.f, 0.f, 0.f, 0.f};
            f32x4 ah1 = (f32x4){0.f, 0.f, 0.f, 0.f};
            f32x4 al0 = (f32x4){0.f, 0.f, 0.f, 0.f};
            f32x4 al1 = (f32x4){0.f, 0.f, 0.f, 0.f};
            const bf16_t* shb = sW + (size_t)nt * KS * 512 + lane * 8;      // nt<8
            const bf16_t* ghb = whi + (size_t)nt * KS * 512 + lane * 8;     // nt>=8
            const bf16_t* glb = wlo + (size_t)nt * KS * 512 + lane * 8;
#pragma unroll
            for (int ks = 0; ks < KS; ks++) {
                bf16x8 wh;
                if (nt < 8) wh = *(const bf16x8*)(shb + ks * 512);
                else        wh = *(const bf16x8*)(ghb + ks * 512);
                bf16x8 wl = *(const bf16x8*)(glb + ks * 512);
                ah0 = __builtin_amdgcn_mfma_f32_16x16x32_bf16(a[0][ks], wh, ah0, 0, 0, 0);
                ah1 = __builtin_amdgcn_mfma_f32_16x16x32_bf16(a[1][ks], wh, ah1, 0, 0, 0);
                al0 = __builtin_amdgcn_mfma_f32_16x16x32_bf16(a[0][ks], wl, al0, 0, 0, 0);
                al1 = __builtin_amdgcn_mfma_f32_16x16x32_bf16(a[1][ks], wl, al1, 0, 0, 0);
            }
            const float bb = bias[nt * 16 + cl];
            const int colL = nti * 16 + cl;
#pragma unroll
            for (int r = 0; r < 4; r++) {
                float v0 = fmaxf(ah0[r] + al0[r] + bb, 0.f);
                float v1 = fmaxf(ah1[r] + al1[r] + bb, 0.f);
                sC[(rbase + rl + r) * 72 + colL]      = f2bf(v0);
                sC[(rbase + 16 + rl + r) * 72 + colL] = f2bf(v1);
            }
        }
        __syncthreads();
        // flush 256 rows x 64 cols, coalesced 128B bursts per row
#pragma unroll
        for (int i = 0; i < 4; i++) {
            const int idx = t + i * 512;
            const int row = idx >> 3, u = idx & 7;
            uint4 v = *(const uint4*)(sC + row * 72 + u * 8);
            *(uint4*)(C + (size_t)(br0 + row) * DH + g * 64 + u * 8) = v;
        }
        __syncthreads();
    }
}

// ---------------------------------------------------------------- pooling
// one block (1024 threads) per graph: thread = (row-group r=t>>5, col-chunk c=t&31)

__global__ __launch_bounds__(1024) void k_pool(
    const bf16_t* __restrict__ h, const int* __restrict__ gstart,
    float* __restrict__ pool /* [NG][512] mean||max */)
{
    __shared__ float ssum[32][DH];
    __shared__ float smax[32][DH];
    int g = blockIdx.x;
    int t = threadIdx.x;
    int c = t & 31;                 // 8-dim chunk
    int r = t >> 5;                 // row group
    int s = gstart[g], e = gstart[g + 1];
    float sum[8], mx[8];
#pragma unroll
    for (int j = 0; j < 8; j++) { sum[j] = 0.f; mx[j] = 0.f; }  // h>=0 post-ReLU
    for (int i = s + r; i < e; i += 32) {
        uint4 v = *(const uint4*)(h + (size_t)i * DH + c * 8);
        float f[8]; unpack8(v, f);
#pragma unroll
        for (int j = 0; j < 8; j++) { sum[j] += f[j]; mx[j] = fmaxf(mx[j], f[j]); }
    }
#pragma unroll
    for (int j = 0; j < 8; j++) { ssum[r][c * 8 + j] = sum[j]; smax[r][c * 8 + j] = mx[j]; }
    __syncthreads();
#pragma unroll
    for (int off = 16; off > 0; off >>= 1) {
        if (r < off) {
#pragma unroll
            for (int j = 0; j < 8; j++) {
                int d = c * 8 + j;
                ssum[r][d] += ssum[r + off][d];
                smax[r][d] = fmaxf(smax[r][d], smax[r + off][d]);
            }
        }
        __syncthreads();
    }
    if (r == 0) {
        float inv = 1.0f / fmaxf((float)(e - s), 1.0f);
#pragma unroll
        for (int j = 0; j < 8; j++) {
            int d = c * 8 + j;
            pool[(size_t)g * 512 + d]       = ssum[0][d] * inv;
            pool[(size_t)g * 512 + 256 + d] = smax[0][d];
        }
    }
}

// -------------------------------------------------------------- classifier

__global__ __launch_bounds__(256) void k_classify(
    const float* __restrict__ pool, const float* __restrict__ cw0,
    const float* __restrict__ cb0, const float* __restrict__ cw1,
    const float* __restrict__ cb1, float* __restrict__ out)
{
    __shared__ float gf[512];
    __shared__ float red[2][4];
    int g = blockIdx.x;
    int t = threadIdx.x;
    gf[t]       = pool[(size_t)g * 512 + t];
    gf[t + 256] = pool[(size_t)g * 512 + 256 + t];
    __syncthreads();
    float acc = cb0[t];
#pragma unroll 8
    for (int k = 0; k < 512; ++k)
        acc = fmaf(gf[k], cw0[(size_t)k * DH + t], acc);
    float hc = fmaxf(acc, 0.f);
    float p0 = hc * cw1[t * 2 + 0];
    float p1 = hc * cw1[t * 2 + 1];
    for (int off = 32; off > 0; off >>= 1) {
        p0 += __shfl_down(p0, off, 64);
        p1 += __shfl_down(p1, off, 64);
    }
    int wave = t >> 6;
    if ((t & 63) == 0) { red[0][wave] = p0; red[1][wave] = p1; }
    __syncthreads();
    if (t == 0) {
        float s0 = cb1[0], s1 = cb1[1];
#pragma unroll
        for (int w = 0; w < 4; w++) { s0 += red[0][w]; s1 += red[1][w]; }
        out[g * 2 + 0] = s0;
        out[g * 2 + 1] = s1;
    }
}

// ------------------------------------------------------------------ launch

extern "C" void kernel_launch(void* const* d_in, const int* in_sizes, int n_in,
                              void* d_out, int out_size, void* d_ws, size_t ws_size,
                              hipStream_t stream)
{
    const int*   node_ids = (const int*)d_in[0];
    const int*   edge_src = (const int*)d_in[1];      // edge_index[0]
    const int*   edge_dst = edge_src + NE;            // edge_index[1]
    const int*   batch    = (const int*)d_in[2];
    const float* emb = (const float*)d_in[3];
    const float* w0  = (const float*)d_in[4];
    const float* b0  = (const float*)d_in[5];
    const float* w1  = (const float*)d_in[6];
    const float* b1  = (const float*)d_in[7];
    const float* w2  = (const float*)d_in[8];
    const float* b2  = (const float*)d_in[9];
    const float* w3  = (const float*)d_in[10];
    const float* b3  = (const float*)d_in[11];
    const float* cw0 = (const float*)d_in[12];
    const float* cb0 = (const float*)d_in[13];
    const float* cw1 = (const float*)d_in[14];
    const float* cb1 = (const float*)d_in[15];
    float* out = (float*)d_out;

    char* p = (char*)d_ws;
    auto alloc = [&](size_t b) -> void* {
        void* r = (void*)p;
        p += (b + 255) & ~(size_t)255;
        return r;
    };
    float*  dinv   = (float*)alloc((size_t)NN * 4);
    int*    rowptr = (int*)alloc((size_t)(NN + 1) * 4);
    int*    cnt    = (int*)alloc((size_t)NN * 4);
    int*    col    = (int*)alloc((size_t)NE * 4);
    int*    bsum   = (int*)alloc(256 * 4);
    int*    gstart = (int*)alloc((NG + 1) * 4);
    float*  pool   = (float*)alloc((size_t)NG * 512 * 4);
    // frag-packed weights: layer0 KS=4, layers1-3 KS=8
    bf16_t* whi0 = (bf16_t*)alloc((size_t)16 * 4 * 512 * 2);
    bf16_t* wlo0 = (bf16_t*)alloc((size_t)16 * 4 * 512 * 2);
    bf16_t* whiL[3]; bf16_t* wloL[3];
    for (int l = 0; l < 3; l++) {
        whiL[l] = (bf16_t*)alloc((size_t)16 * 8 * 512 * 2);
        wloL[l] = (bf16_t*)alloc((size_t)16 * 8 * 512 * 2);
    }
    bf16_t* hA = (bf16_t*)alloc((size_t)NPAD * DH * 2);   // 76.8 MB
    bf16_t* hB = (bf16_t*)alloc((size_t)NPAD * DH * 2);   // 76.8 MB
    (void)ws_size; (void)in_sizes; (void)n_in; (void)out_size;

    // weight fragment prep (tiny)
    k_wprep<<<(16 * 4 * 64 + 255) / 256, 256, 0, stream>>>(w0, 4, whi0, wlo0);
    k_wprep<<<(16 * 8 * 64 + 255) / 256, 256, 0, stream>>>(w1, 8, whiL[0], wloL[0]);
    k_wprep<<<(16 * 8 * 64 + 255) / 256, 256, 0, stream>>>(w2, 8, whiL[1], wloL[1]);
    k_wprep<<<(16 * 8 * 64 + 255) / 256, 256, 0, stream>>>(w3, 8, whiL[2], wloL[2]);

    // degree + CSR (dst-sorted) + graph offsets
    k_zero<<<(NN + 255) / 256, 256, 0, stream>>>(cnt, NN);
    k_hist<<<(NE + 255) / 256, 256, 0, stream>>>(edge_dst, cnt);
    k_dinv<<<(NN + 255) / 256, 256, 0, stream>>>(cnt, dinv);
    const int NB = (NN + SCAN_CHUNK - 1) / SCAN_CHUNK;   // 147
    k_scan1<<<NB, 256, 0, stream>>>(cnt, bsum);
    k_scan2<<<1, 64, 0, stream>>>(bsum, NB);
    k_scan3<<<NB, 256, 0, stream>>>(cnt, bsum, rowptr);
    k_zero<<<(NN + 255) / 256, 256, 0, stream>>>(cnt, NN);   // reuse as fill cursor
    k_scatter<<<(NE + 255) / 256, 256, 0, stream>>>(edge_src, edge_dst, rowptr, cnt, col);
    k_gstart<<<(NN + 255) / 256, 256, 0, stream>>>(batch, gstart);

    // layer 0: fused (emb fp32 gather agg, K=128) -> hB
    k_fused<4, true><<<NPAD / 256, 512, 0, stream>>>(
        nullptr, emb, node_ids, dinv, rowptr, col, whi0, wlo0, b0, hB);
    // layer 1: hB -> hA
    k_fused<8, false><<<NPAD / 256, 512, 0, stream>>>(
        hB, nullptr, nullptr, dinv, rowptr, col, whiL[0], wloL[0], b1, hA);
    // layer 2: hA -> hB
    k_fused<8, false><<<NPAD / 256, 512, 0, stream>>>(
        hA, nullptr, nullptr, dinv, rowptr, col, whiL[1], wloL[1], b2, hB);
    // layer 3: hB -> hA
    k_fused<8, false><<<NPAD / 256, 512, 0, stream>>>(
        hB, nullptr, nullptr, dinv, rowptr, col, whiL[2], wloL[2], b3, hA);

    // pooling + classifier
    k_pool<<<NG, 1024, 0, stream>>>(hA, gstart, pool);
    k_classify<<<NG, 256, 0, stream>>>(pool, cw0, cb0, cw1, cb1, out);
}

// Round 9
// 560.304 us; speedup vs baseline: 1.6577x; 1.6577x over previous
//
#include <hip/hip_runtime.h>
#include <stdint.h>
#include <stddef.h>

#define NN 150000   // nodes
#define NPAD 150016 // padded rows (= 586 * 256)
#define NE 300000   // edges
#define NG 256      // graphs
#define DE 128      // embedding dim
#define DH 256      // hidden dim

typedef unsigned short bf16_t;
typedef __attribute__((ext_vector_type(8))) short bf16x8;
typedef __attribute__((ext_vector_type(4))) float f32x4;

__device__ __forceinline__ float bf2f(unsigned int u) {
    union { unsigned int i; float f; } v; v.i = u << 16; return v.f;
}
__device__ __forceinline__ bf16_t f2bf(float f) {
    union { float f; unsigned int i; } v; v.f = f;
    unsigned int x = v.i;
    return (bf16_t)((x + 0x7fffu + ((x >> 16) & 1u)) >> 16);   // RNE
}

// ---------------------------------------------------------------- utility

__global__ void k_zero(int* __restrict__ p, int n) {
    int i = blockIdx.x * blockDim.x + threadIdx.x;
    if (i < n) p[i] = 0;
}

// ---------------------------------------------------------------- precompute

__global__ void k_hist(const int* __restrict__ dst, int* __restrict__ cnt) {
    int e = blockIdx.x * blockDim.x + threadIdx.x;
    if (e < NE) atomicAdd(&cnt[dst[e]], 1);
}

__global__ void k_dinv(const int* __restrict__ cnt, float* __restrict__ dinv) {
    int i = blockIdx.x * blockDim.x + threadIdx.x;
    if (i < NN) dinv[i] = rsqrtf((float)(cnt[i] + 1));  // +1 self-loop; deg>=1
}

#define SCAN_CHUNK 1024
__global__ void k_scan1(const int* __restrict__ cnt, int* __restrict__ bsum) {
    __shared__ int sd[256];
    int base = blockIdx.x * SCAN_CHUNK;
    int t = threadIdx.x;
    int s = 0;
#pragma unroll
    for (int j = 0; j < 4; j++) {
        int i = base + t * 4 + j;
        if (i < NN) s += cnt[i];
    }
    sd[t] = s; __syncthreads();
    for (int off = 128; off > 0; off >>= 1) {
        if (t < off) sd[t] += sd[t + off];
        __syncthreads();
    }
    if (t == 0) bsum[blockIdx.x] = sd[0];
}

__global__ void k_scan2(int* __restrict__ bsum, int nb) {
    if (threadIdx.x == 0) {
        int acc = 0;
        for (int b = 0; b < nb; b++) { int v = bsum[b]; bsum[b] = acc; acc += v; }
    }
}

// also zeroes cnt after reading (fill-cursor prep for k_scatter)
__global__ void k_scan3(int* __restrict__ cnt, const int* __restrict__ bsum,
                        int* __restrict__ rowptr) {
    __shared__ int sd[256];
    int base = blockIdx.x * SCAN_CHUNK;
    int t = threadIdx.x;
    int v[4]; int s = 0;
#pragma unroll
    for (int j = 0; j < 4; j++) {
        int i = base + t * 4 + j;
        v[j] = (i < NN) ? cnt[i] : 0;
        s += v[j];
    }
    sd[t] = s; __syncthreads();
    for (int off = 1; off < 256; off <<= 1) {
        int x = (t >= off) ? sd[t - off] : 0;
        __syncthreads();
        sd[t] += x;
        __syncthreads();
    }
    int pre = bsum[blockIdx.x] + ((t == 0) ? 0 : sd[t - 1]);
#pragma unroll
    for (int j = 0; j < 4; j++) {
        int i = base + t * 4 + j;
        if (i < NN) { rowptr[i] = pre; pre += v[j]; cnt[i] = 0; }
    }
    if (blockIdx.x == 0 && t == 0) rowptr[NN] = NE;
}

__global__ void k_scatter(const int* __restrict__ src, const int* __restrict__ dst,
                          const int* __restrict__ rowptr, int* __restrict__ fill,
                          int* __restrict__ col) {
    int e = blockIdx.x * blockDim.x + threadIdx.x;
    if (e < NE) {
        int d = dst[e];
        int p = rowptr[d] + atomicAdd(&fill[d], 1);
        col[p] = src[e];
    }
}

__global__ void k_gstart(const int* __restrict__ batch, int* __restrict__ gstart) {
    int i = blockIdx.x * blockDim.x + threadIdx.x;
    if (i >= NN) return;
    int g = batch[i];
    int gp = (i == 0) ? -1 : batch[i - 1];
    for (int gg = gp + 1; gg <= g; ++gg) gstart[gg] = i;
    if (i == NN - 1) {
        for (int gg = g + 1; gg <= NG; ++gg) gstart[gg] = NN;
    }
}

// embedding lookup, fp32 -> bf16, 8 elems/thread
__global__ void k_embed(const int* __restrict__ ids, const float* __restrict__ emb,
                        bf16_t* __restrict__ h) {
    int idx = blockIdx.x * blockDim.x + threadIdx.x;   // over NN * 16
    if (idx >= NN * (DE / 8)) return;
    int i = idx >> 4, c = idx & 15;
    const float4* s = (const float4*)(emb + (size_t)ids[i] * DE + c * 8);
    float4 v0 = s[0], v1 = s[1];
    uint4 o;
    o.x = (unsigned)f2bf(v0.x) | ((unsigned)f2bf(v0.y) << 16);
    o.y = (unsigned)f2bf(v0.z) | ((unsigned)f2bf(v0.w) << 16);
    o.z = (unsigned)f2bf(v1.x) | ((unsigned)f2bf(v1.y) << 16);
    o.w = (unsigned)f2bf(v1.z) | ((unsigned)f2bf(v1.w) << 16);
    *(uint4*)(h + (size_t)i * DE + c * 8) = o;
}

// ------------------------------------------------------- weight fragment prep
// W[K][256] fp32 -> frag-ordered bf16 hi/lo, linear in q = nt*KS + ks (nt 0..15):
// element (q,l,j) = W[ks*32 + (l>>4)*8 + j][nt*16 + (l&15)]

__global__ void k_wprep(const float* __restrict__ W, int KS,
                        bf16_t* __restrict__ whi, bf16_t* __restrict__ wlo) {
    int tid = blockIdx.x * blockDim.x + threadIdx.x;
    int total = 16 * KS * 64;
    if (tid >= total) return;
    int l = tid & 63, q = tid >> 6;
    int ks = q % KS;
    int nt = q / KS;
    int row0 = ks * 32 + (l >> 4) * 8;
    int colc = nt * 16 + (l & 15);
    unsigned hi[8], lo[8];
#pragma unroll
    for (int j = 0; j < 8; j++) {
        float v = W[(size_t)(row0 + j) * DH + colc];
        bf16_t h = f2bf(v);
        float rem = v - bf2f(h);
        hi[j] = h;
        lo[j] = f2bf(rem);
    }
    uint4 ph, pl;
    ph.x = hi[0] | (hi[1] << 16); ph.y = hi[2] | (hi[3] << 16);
    ph.z = hi[4] | (hi[5] << 16); ph.w = hi[6] | (hi[7] << 16);
    pl.x = lo[0] | (lo[1] << 16); pl.y = lo[2] | (lo[3] << 16);
    pl.z = lo[4] | (lo[5] << 16); pl.w = lo[6] | (lo[7] << 16);
    ((uint4*)whi)[q * 64 + l] = ph;
    ((uint4*)wlo)[q * 64 + l] = pl;
}

__device__ __forceinline__ void unpack8(uint4 u, float* f) {
    f[0] = bf2f(u.x & 0xffffu); f[1] = bf2f(u.x >> 16);
    f[2] = bf2f(u.y & 0xffffu); f[3] = bf2f(u.y >> 16);
    f[4] = bf2f(u.z & 0xffffu); f[5] = bf2f(u.z >> 16);
    f[6] = bf2f(u.w & 0xffffu); f[7] = bf2f(u.w >> 16);
}

// ------------------------------------------------------------- aggregation
// y[i] = dinv[i] * ( dinv[i]*x[i] + sum_{e: dst=i} dinv[src_e]*x[src_e] )
// thread = (node, chunk of 8 bf16); coalesced 16B gathers per neighbor.

template <int W>
__global__ void k_agg(const bf16_t* __restrict__ x, const float* __restrict__ dinv,
                      const int* __restrict__ rowptr, const int* __restrict__ col,
                      bf16_t* __restrict__ y) {
    constexpr int SH = (W == 128) ? 4 : 5;     // chunks per node = W/8
    int idx = blockIdx.x * 256 + threadIdx.x;
    if (idx >= NN * (W / 8)) return;
    int node = idx >> SH;
    int c = idx & ((W / 8) - 1);
    size_t off = (size_t)c * 8;
    float di = dinv[node];
    float acc[8];
    uint4 u = *(const uint4*)(x + (size_t)node * W + off);
    unpack8(u, acc);
#pragma unroll
    for (int j = 0; j < 8; j++) acc[j] *= di;
    int r0 = rowptr[node], r1 = rowptr[node + 1];
    for (int r = r0; r < r1; ++r) {
        int s = col[r];
        float ds = dinv[s];
        float f[8];
        uint4 v = *(const uint4*)(x + (size_t)s * W + off);
        unpack8(v, f);
#pragma unroll
        for (int j = 0; j < 8; j++) acc[j] = fmaf(ds, f[j], acc[j]);
    }
    uint4 o;
    o.x = (unsigned)f2bf(di * acc[0]) | ((unsigned)f2bf(di * acc[1]) << 16);
    o.y = (unsigned)f2bf(di * acc[2]) | ((unsigned)f2bf(di * acc[3]) << 16);
    o.z = (unsigned)f2bf(di * acc[4]) | ((unsigned)f2bf(di * acc[5]) << 16);
    o.w = (unsigned)f2bf(di * acc[6]) | ((unsigned)f2bf(di * acc[7]) << 16);
    *(uint4*)(y + (size_t)node * W + off) = o;
}

// ------------------------------------------------------------------- GEMM
// C[NPAD x 256] = relu(A[NPAD x K] @ W[K x 256] + bias)
// A,C bf16; W pre-packed hi/lo bf16 fragments.
// Block: 512 threads = 8 waves; wave owns 32 rows; block = 256 rows x 128 cols
// (nh = blockIdx.y). W_hi staged in LDS 4 nt at a time (32 KB, restaged once);
// W_lo streamed from L2. A-frags held in VGPRs. Epilogue staged through a
// separate 36 KB sC region, flushed as 128B/row coalesced bursts every 4 nt.
// LDS total 68 KB (KS=8) -> 2 blocks/CU.

template <int KS>
__global__ __launch_bounds__(512) void k_gemm_mfma(
    const bf16_t* __restrict__ A, const bf16_t* __restrict__ whi,
    const bf16_t* __restrict__ wlo, const float* __restrict__ bias,
    bf16_t* __restrict__ C)
{
    constexpr int K = KS * 32;
    constexpr int SWB = 4 * KS * 512 * 2;     // W_hi staging: 4 nt (32 KB @KS=8)
    constexpr int SCB = 256 * 72 * 2;         // C staging: 64 cols + pad (36 KB)
    __shared__ __align__(16) char smem[SWB + SCB];
    bf16_t* sW = (bf16_t*)smem;
    bf16_t* sC = (bf16_t*)(smem + SWB);

    const int t = threadIdx.x;
    const int lane = t & 63;
    const int wave = t >> 6;                  // 0..7
    const int nh = blockIdx.y;
    const int br0 = blockIdx.x * 256;

    // stage W_hi group 0 (nt = nh*8 + 0..3)
    {
        const uint4* g0 = (const uint4*)whi + ((size_t)nh * 8) * KS * 64;
        uint4* sd = (uint4*)sW;
#pragma unroll
        for (int i = 0; i < (4 * KS * 64) / 512; i++)
            sd[t + i * 512] = g0[t + i * 512];
    }

    // A fragments: wave's 32 rows (2 subtiles of 16), full K. 4*KS VGPRs.
    const int r0 = br0 + wave * 32;
    bf16x8 a[2][KS];
#pragma unroll
    for (int s = 0; s < 2; s++) {
        const bf16_t* ap = A + (size_t)(r0 + s * 16 + (lane & 15)) * K + (lane >> 4) * 8;
#pragma unroll
        for (int ks = 0; ks < KS; ks++)
            a[s][ks] = *(const bf16x8*)(ap + ks * 32);
    }
    __syncthreads();

    const int cl = lane & 15;
    const int rl = (lane >> 4) * 4;
    const int lr0 = wave * 32 + rl;           // local row base (sub0); sub1 = +16

#pragma unroll 1
    for (int g = 0; g < 2; g++) {
#pragma unroll
        for (int ntl = 0; ntl < 4; ntl++) {
            const int nt = g * 4 + ntl;       // 0..7 within this nh
            f32x4 ah0 = (f32x4){0.f, 0.f, 0.f, 0.f};
            f32x4 ah1 = (f32x4){0.f, 0.f, 0.f, 0.f};
            f32x4 al0 = (f32x4){0.f, 0.f, 0.f, 0.f};
            f32x4 al1 = (f32x4){0.f, 0.f, 0.f, 0.f};
            const bf16_t* shb = sW + (size_t)ntl * KS * 512 + lane * 8;
            const bf16_t* glb = wlo + ((size_t)(nh * 8 + nt) * KS) * 512 + lane * 8;
#pragma unroll
            for (int ks = 0; ks < KS; ks++) {
                bf16x8 wh = *(const bf16x8*)(shb + ks * 512);
                bf16x8 wl = *(const bf16x8*)(glb + ks * 512);
                ah0 = __builtin_amdgcn_mfma_f32_16x16x32_bf16(a[0][ks], wh, ah0, 0, 0, 0);
                ah1 = __builtin_amdgcn_mfma_f32_16x16x32_bf16(a[1][ks], wh, ah1, 0, 0, 0);
                al0 = __builtin_amdgcn_mfma_f32_16x16x32_bf16(a[0][ks], wl, al0, 0, 0, 0);
                al1 = __builtin_amdgcn_mfma_f32_16x16x32_bf16(a[1][ks], wl, al1, 0, 0, 0);
            }
            const float bb = bias[nh * 128 + nt * 16 + cl];
            const int colL = ntl * 16 + cl;
#pragma unroll
            for (int r = 0; r < 4; r++) {
                float v0 = fmaxf(ah0[r] + al0[r] + bb, 0.f);
                float v1 = fmaxf(ah1[r] + al1[r] + bb, 0.f);
                sC[(lr0 + r) * 72 + colL]      = f2bf(v0);
                sC[(lr0 + 16 + r) * 72 + colL] = f2bf(v1);
            }
        }
        __syncthreads();
        // flush 256 rows x 64 cols: 128B contiguous per row, rows sequential
#pragma unroll
        for (int i = 0; i < 4; i++) {
            const int idx = t + i * 512;
            const int row = idx >> 3, u = idx & 7;
            uint4 v = *(const uint4*)(sC + row * 72 + u * 8);
            *(uint4*)(C + (size_t)(br0 + row) * DH + nh * 128 + g * 64 + u * 8) = v;
        }
        if (g == 0) {
            // restage W_hi group 1 (nt = nh*8 + 4..7); old sW reads done at barrier
            const uint4* g1 = (const uint4*)whi + ((size_t)(nh * 8 + 4)) * KS * 64;
            uint4* sd = (uint4*)sW;
#pragma unroll
            for (int i = 0; i < (4 * KS * 64) / 512; i++)
                sd[t + i * 512] = g1[t + i * 512];
        }
        __syncthreads();
    }
}

// ---------------------------------------------------------------- pooling
// one block (1024 threads) per graph: thread = (row-group r=t>>5, col-chunk c=t&31)

__global__ __launch_bounds__(1024) void k_pool(
    const bf16_t* __restrict__ h, const int* __restrict__ gstart,
    float* __restrict__ pool /* [NG][512] mean||max */)
{
    __shared__ float ssum[32][DH];
    __shared__ float smax[32][DH];
    int g = blockIdx.x;
    int t = threadIdx.x;
    int c = t & 31;                 // 8-dim chunk
    int r = t >> 5;                 // row group
    int s = gstart[g], e = gstart[g + 1];
    float sum[8], mx[8];
#pragma unroll
    for (int j = 0; j < 8; j++) { sum[j] = 0.f; mx[j] = 0.f; }  // h>=0 post-ReLU
    for (int i = s + r; i < e; i += 32) {
        uint4 v = *(const uint4*)(h + (size_t)i * DH + c * 8);
        float f[8]; unpack8(v, f);
#pragma unroll
        for (int j = 0; j < 8; j++) { sum[j] += f[j]; mx[j] = fmaxf(mx[j], f[j]); }
    }
#pragma unroll
    for (int j = 0; j < 8; j++) { ssum[r][c * 8 + j] = sum[j]; smax[r][c * 8 + j] = mx[j]; }
    __syncthreads();
#pragma unroll
    for (int off = 16; off > 0; off >>= 1) {
        if (r < off) {
#pragma unroll
            for (int j = 0; j < 8; j++) {
                int d = c * 8 + j;
                ssum[r][d] += ssum[r + off][d];
                smax[r][d] = fmaxf(smax[r][d], smax[r + off][d]);
            }
        }
        __syncthreads();
    }
    if (r == 0) {
        float inv = 1.0f / fmaxf((float)(e - s), 1.0f);
#pragma unroll
        for (int j = 0; j < 8; j++) {
            int d = c * 8 + j;
            pool[(size_t)g * 512 + d]       = ssum[0][d] * inv;
            pool[(size_t)g * 512 + 256 + d] = smax[0][d];
        }
    }
}

// -------------------------------------------------------------- classifier

__global__ __launch_bounds__(256) void k_classify(
    const float* __restrict__ pool, const float* __restrict__ cw0,
    const float* __restrict__ cb0, const float* __restrict__ cw1,
    const float* __restrict__ cb1, float* __restrict__ out)
{
    __shared__ float gf[512];
    __shared__ float red[2][4];
    int g = blockIdx.x;
    int t = threadIdx.x;
    gf[t]       = pool[(size_t)g * 512 + t];
    gf[t + 256] = pool[(size_t)g * 512 + 256 + t];
    __syncthreads();
    float acc = cb0[t];
#pragma unroll 8
    for (int k = 0; k < 512; ++k)
        acc = fmaf(gf[k], cw0[(size_t)k * DH + t], acc);
    float hc = fmaxf(acc, 0.f);
    float p0 = hc * cw1[t * 2 + 0];
    float p1 = hc * cw1[t * 2 + 1];
    for (int off = 32; off > 0; off >>= 1) {
        p0 += __shfl_down(p0, off, 64);
        p1 += __shfl_down(p1, off, 64);
    }
    int wave = t >> 6;
    if ((t & 63) == 0) { red[0][wave] = p0; red[1][wave] = p1; }
    __syncthreads();
    if (t == 0) {
        float s0 = cb1[0], s1 = cb1[1];
#pragma unroll
        for (int w = 0; w < 4; w++) { s0 += red[0][w]; s1 += red[1][w]; }
        out[g * 2 + 0] = s0;
        out[g * 2 + 1] = s1;
    }
}

// ------------------------------------------------------------------ launch

extern "C" void kernel_launch(void* const* d_in, const int* in_sizes, int n_in,
                              void* d_out, int out_size, void* d_ws, size_t ws_size,
                              hipStream_t stream)
{
    const int*   node_ids = (const int*)d_in[0];
    const int*   edge_src = (const int*)d_in[1];      // edge_index[0]
    const int*   edge_dst = edge_src + NE;            // edge_index[1]
    const int*   batch    = (const int*)d_in[2];
    const float* emb = (const float*)d_in[3];
    const float* w0  = (const float*)d_in[4];
    const float* b0  = (const float*)d_in[5];
    const float* w1  = (const float*)d_in[6];
    const float* b1  = (const float*)d_in[7];
    const float* w2  = (const float*)d_in[8];
    const float* b2  = (const float*)d_in[9];
    const float* w3  = (const float*)d_in[10];
    const float* b3  = (const float*)d_in[11];
    const float* cw0 = (const float*)d_in[12];
    const float* cb0 = (const float*)d_in[13];
    const float* cw1 = (const float*)d_in[14];
    const float* cb1 = (const float*)d_in[15];
    float* out = (float*)d_out;

    char* p = (char*)d_ws;
    auto alloc = [&](size_t b) -> void* {
        void* r = (void*)p;
        p += (b + 255) & ~(size_t)255;
        return r;
    };
    float*  dinv   = (float*)alloc((size_t)NN * 4);
    int*    rowptr = (int*)alloc((size_t)(NN + 1) * 4);
    int*    cnt    = (int*)alloc((size_t)NN * 4);
    int*    col    = (int*)alloc((size_t)NE * 4);
    int*    bsum   = (int*)alloc(256 * 4);
    int*    gstart = (int*)alloc((NG + 1) * 4);
    float*  pool   = (float*)alloc((size_t)NG * 512 * 4);
    // frag-packed weights: layer0 KS=4, layers1-3 KS=8
    bf16_t* whi0 = (bf16_t*)alloc((size_t)16 * 4 * 512 * 2);
    bf16_t* wlo0 = (bf16_t*)alloc((size_t)16 * 4 * 512 * 2);
    bf16_t* whiL[3]; bf16_t* wloL[3];
    for (int l = 0; l < 3; l++) {
        whiL[l] = (bf16_t*)alloc((size_t)16 * 8 * 512 * 2);
        wloL[l] = (bf16_t*)alloc((size_t)16 * 8 * 512 * 2);
    }
    bf16_t* hA = (bf16_t*)alloc((size_t)NPAD * DH * 2);   // 76.8 MB
    bf16_t* hB = (bf16_t*)alloc((size_t)NPAD * DH * 2);   // 76.8 MB
    (void)ws_size; (void)in_sizes; (void)n_in; (void)out_size;

    // weight fragment prep (tiny)
    k_wprep<<<(16 * 4 * 64 + 255) / 256, 256, 0, stream>>>(w0, 4, whi0, wlo0);
    k_wprep<<<(16 * 8 * 64 + 255) / 256, 256, 0, stream>>>(w1, 8, whiL[0], wloL[0]);
    k_wprep<<<(16 * 8 * 64 + 255) / 256, 256, 0, stream>>>(w2, 8, whiL[1], wloL[1]);
    k_wprep<<<(16 * 8 * 64 + 255) / 256, 256, 0, stream>>>(w3, 8, whiL[2], wloL[2]);

    // degree + CSR (dst-sorted) + graph offsets
    k_zero<<<(NN + 255) / 256, 256, 0, stream>>>(cnt, NN);
    k_hist<<<(NE + 255) / 256, 256, 0, stream>>>(edge_dst, cnt);
    k_dinv<<<(NN + 255) / 256, 256, 0, stream>>>(cnt, dinv);
    const int NB = (NN + SCAN_CHUNK - 1) / SCAN_CHUNK;   // 147
    k_scan1<<<NB, 256, 0, stream>>>(cnt, bsum);
    k_scan2<<<1, 64, 0, stream>>>(bsum, NB);
    k_scan3<<<NB, 256, 0, stream>>>(cnt, bsum, rowptr);  // zeroes cnt for scatter
    k_scatter<<<(NE + 255) / 256, 256, 0, stream>>>(edge_src, edge_dst, rowptr, cnt, col);
    k_gstart<<<(NN + 255) / 256, 256, 0, stream>>>(batch, gstart);

    // embedding lookup -> hA [N,128] bf16
    k_embed<<<(NN * (DE / 8) + 255) / 256, 256, 0, stream>>>(node_ids, emb, hA);

    // layer 0: aggregate (width 128) then transform 128->256
    k_agg<128><<<(NN * 16 + 255) / 256, 256, 0, stream>>>(hA, dinv, rowptr, col, hB);
    k_gemm_mfma<4><<<dim3(NPAD / 256, 2), 512, 0, stream>>>(hB, whi0, wlo0, b0, hA);

    // layers 1..3: aggregate (width 256) then transform 256->256
    for (int l = 0; l < 3; l++) {
        const float* bs = (l == 0) ? b1 : (l == 1) ? b2 : b3;
        k_agg<256><<<(NN * 32 + 255) / 256, 256, 0, stream>>>(hA, dinv, rowptr, col, hB);
        k_gemm_mfma<8><<<dim3(NPAD / 256, 2), 512, 0, stream>>>(hB, whiL[l], wloL[l], bs, hA);
    }

    // pooling + classifier
    k_pool<<<NG, 1024, 0, stream>>>(hA, gstart, pool);
    k_classify<<<NG, 256, 0, stream>>>(pool, cw0, cb0, cw1, cb1, out);
}